// Round 2
// baseline (9.846 us; speedup 1.0000x reference)
//
#include <hip/hip_runtime.h>

// QuantumDifficultyAdjuster — closed-form collapse of the product-state circuit.
//
// out_h = prod_{q=0}^{2h} z_q,  z_q = cos(th_q1)*cos(x_q) - sin(th_q1)*cos(th_q0)*sin(x_q)
// y = q_out @ fc_w.T + fc_b
//
// v3: 2 rows per thread, block=256.
//  - 65536 threads = 1024 waves = 1 wave per SIMD across all 256 CUs
//    (v2's 512 waves left half the SIMDs idle; cold-HBM load latency was
//    fully exposed). Doubles the number of independent memory streams.
//  - loads stay vectorized: 4x float4 (64B/thread contiguous).
//  - stores stay dense: 3x float2 (24B/thread contiguous, 8B-aligned).
//  - theta trig (21 wave-uniform trans ops) amortized over 2 rows.
__global__ __launch_bounds__(256) void qda_kernel(
    const float* __restrict__ x,      // (B, 8)
    const float* __restrict__ theta,  // (24,)
    const float* __restrict__ fc_w,   // (3, 4) row-major
    const float* __restrict__ fc_b,   // (3,)
    float* __restrict__ out,          // (B, 3)
    int batch)
{
    const int i = blockIdx.x * blockDim.x + threadIdx.x;
    const int base = i * 2;                 // first row of this thread's pair
    if (base >= batch) return;

    // ---- wave-uniform coefficients ----
    float A[7], Bc[7];
#pragma unroll
    for (int q = 0; q < 7; ++q) {
        float th0 = theta[3 * q + 0];       // wave-uniform -> scalar loads
        float th1 = theta[3 * q + 1];
        A[q]  = __cosf(th1);
        Bc[q] = __sinf(th1) * __cosf(th0);
    }
    const float w00 = fc_w[0], w01 = fc_w[1], w02 = fc_w[2],  w03 = fc_w[3];
    const float w10 = fc_w[4], w11 = fc_w[5], w12 = fc_w[6],  w13 = fc_w[7];
    const float w20 = fc_w[8], w21 = fc_w[9], w22 = fc_w[10], w23 = fc_w[11];
    const float b0 = fc_b[0], b1 = fc_b[1], b2 = fc_b[2];

    if (base + 2 <= batch) {
        // ---- fast path: 2 full rows, vectorized IO ----
        const float4* xp = reinterpret_cast<const float4*>(x + (size_t)base * 8);
        float xv[16];
#pragma unroll
        for (int k = 0; k < 4; ++k) {
            float4 v = xp[k];               // 4 independent 16B loads
            xv[4 * k + 0] = v.x;
            xv[4 * k + 1] = v.y;
            xv[4 * k + 2] = v.z;
            xv[4 * k + 3] = v.w;
        }

        float y[6];
#pragma unroll
        for (int r = 0; r < 2; ++r) {
            float z[7];
#pragma unroll
            for (int q = 0; q < 7; ++q) {
                float s, c;
                __sincosf(xv[8 * r + q], &s, &c);
                z[q] = fmaf(A[q], c, -Bc[q] * s);
            }
            float h0 = z[0];
            float h1 = h0 * z[1] * z[2];
            float h2 = h1 * z[3] * z[4];
            float h3 = h2 * z[5] * z[6];
            y[3 * r + 0] = fmaf(w00, h0, fmaf(w01, h1, fmaf(w02, h2, fmaf(w03, h3, b0))));
            y[3 * r + 1] = fmaf(w10, h0, fmaf(w11, h1, fmaf(w12, h2, fmaf(w13, h3, b1))));
            y[3 * r + 2] = fmaf(w20, h0, fmaf(w21, h1, fmaf(w22, h2, fmaf(w23, h3, b2))));
        }

        float2* op = reinterpret_cast<float2*>(out + (size_t)base * 3);
        op[0] = make_float2(y[0], y[1]);
        op[1] = make_float2(y[2], y[3]);
        op[2] = make_float2(y[4], y[5]);
    } else {
        // ---- tail path (batch odd): scalar per row ----
        for (int row = base; row < batch; ++row) {
            const float* xs = x + (size_t)row * 8;
            float z[7];
#pragma unroll
            for (int q = 0; q < 7; ++q) {
                float s, c;
                __sincosf(xs[q], &s, &c);
                z[q] = fmaf(A[q], c, -Bc[q] * s);
            }
            float h0 = z[0];
            float h1 = h0 * z[1] * z[2];
            float h2 = h1 * z[3] * z[4];
            float h3 = h2 * z[5] * z[6];
            float* op = out + (size_t)row * 3;
            op[0] = fmaf(w00, h0, fmaf(w01, h1, fmaf(w02, h2, fmaf(w03, h3, b0))));
            op[1] = fmaf(w10, h0, fmaf(w11, h1, fmaf(w12, h2, fmaf(w13, h3, b1))));
            op[2] = fmaf(w20, h0, fmaf(w21, h1, fmaf(w22, h2, fmaf(w23, h3, b2))));
        }
    }
}

extern "C" void kernel_launch(void* const* d_in, const int* in_sizes, int n_in,
                              void* d_out, int out_size, void* d_ws, size_t ws_size,
                              hipStream_t stream) {
    const float* x     = (const float*)d_in[0];
    const float* theta = (const float*)d_in[1];
    const float* fc_w  = (const float*)d_in[2];
    const float* fc_b  = (const float*)d_in[3];
    float* out = (float*)d_out;

    int batch = in_sizes[0] / 8;            // x is (B, 8)
    int nthreads = (batch + 1) / 2;         // 2 rows per thread
    int block = 256;
    int grid = (nthreads + block - 1) / block;
    qda_kernel<<<grid, block, 0, stream>>>(x, theta, fc_w, fc_b, out, batch);
}